// Round 11
// baseline (256.891 us; speedup 1.0000x reference)
//
#include <hip/hip_runtime.h>
#include <hip/hip_bf16.h>
#include <cstdint>
#include <cstddef>

// Problem constants (match reference)
constexpr int BB   = 4;
constexpr int NIN  = 4096;
constexpr int MM   = 16384;
constexpr int CIN  = 256;
constexpr int COUT = 128;
constexpr float EPSBN = 1e-5f;

// async global->LDS, 16B per lane (CK-style addrspace casts)
typedef __attribute__((address_space(1))) const uint32_t gu32;
typedef __attribute__((address_space(3))) uint32_t lu32;
__device__ __forceinline__ void gload16(const float* g, float* l) {
    __builtin_amdgcn_global_load_lds((gu32*)g, (lu32*)l, 16, 0, 0);
}

// ---------------------------------------------------------------------------
// prep: transpose weights (Cout,Cin)->(Cin,Cout), fold BN into (s,t),
//       pack xyzin into float4 (2x, 2y, 2z, x^2+y^2+z^2).
//       2x is exact (power-of-2 scale), so (x*2x' + y*2y') + z*2z' is
//       bit-identical to 2*((x*x' + y*y') + z*z') of the reference.
// ---------------------------------------------------------------------------
__global__ __launch_bounds__(256) void prep_kernel(
    const float* __restrict__ w1, const float* __restrict__ w2, const float* __restrict__ w3,
    const float* __restrict__ b1, const float* __restrict__ g1, const float* __restrict__ be1,
    const float* __restrict__ rm1, const float* __restrict__ rv1,
    const float* __restrict__ b2, const float* __restrict__ g2, const float* __restrict__ be2,
    const float* __restrict__ rm2, const float* __restrict__ rv2,
    const float* __restrict__ b3, const float* __restrict__ g3, const float* __restrict__ be3,
    const float* __restrict__ rm3, const float* __restrict__ rv3,
    const float* __restrict__ xyzin,
    float* __restrict__ WT1, float* __restrict__ WT2, float* __restrict__ WT3,
    float* __restrict__ st, float4* __restrict__ packed)
{
    int tid  = blockIdx.x * blockDim.x + threadIdx.x;
    int nthr = gridDim.x * blockDim.x;

    for (int i = tid; i < CIN * COUT; i += nthr)
        WT1[i] = w1[(i & 127) * CIN + (i >> 7)];
    for (int i = tid; i < COUT * COUT; i += nthr)
        WT2[i] = w2[(i & 127) * COUT + (i >> 7)];
    for (int i = tid; i < COUT * COUT; i += nthr)
        WT3[i] = w3[(i & 127) * COUT + (i >> 7)];

    for (int i = tid; i < 3 * COUT; i += nthr) {
        int l = i >> 7, o = i & 127;
        const float* bb = (l == 0) ? b1 : (l == 1) ? b2 : b3;
        const float* gg = (l == 0) ? g1 : (l == 1) ? g2 : g3;
        const float* be = (l == 0) ? be1 : (l == 1) ? be2 : be3;
        const float* rm = (l == 0) ? rm1 : (l == 1) ? rm2 : rm3;
        const float* rv = (l == 0) ? rv1 : (l == 1) ? rv2 : rv3;
        float s = gg[o] / sqrtf(rv[o] + EPSBN);
        st[l * 256 + o]       = s;
        st[l * 256 + 128 + o] = s * (bb[o] - rm[o]) + be[o];
    }

    for (int i = tid; i < BB * NIN; i += nthr) {
        float x = xyzin[i * 3 + 0], y = xyzin[i * 3 + 1], z = xyzin[i * 3 + 2];
        float sn = __fadd_rn(__fadd_rn(__fmul_rn(x, x), __fmul_rn(y, y)), __fmul_rn(z, z));
        packed[i] = make_float4(2.0f * x, 2.0f * y, 2.0f * z, sn);
    }
}

// ---------------------------------------------------------------------------
// mlp layer: out[b,o,n] = relu(s[o]*(sum_k W[o,k]*in[b,k,n]) + t[o])
// block = 256 thr, tile = 128 o x 32 n, thread = 4o x 4n, BK=32.
// Double-buffered async staging via global_load_lds: issue chunk k+1's loads
// BEFORE computing chunk k; ONE barrier per chunk (drains vmcnt+lgkm).
// Hides ~500cy VMEM latency that 2 blocks/CU (grid=512) can't hide via TLP.
// TOUT=true writes point-major (B,N,128).
// ---------------------------------------------------------------------------
template <int CI, bool TOUT>
__global__ __launch_bounds__(256) void mlp_kernel(
    const float* __restrict__ in, const float* __restrict__ WT,
    const float* __restrict__ svec, const float* __restrict__ tvec,
    float* __restrict__ out)
{
    __shared__ float Xs[2][32][32];
    __shared__ float Ws[2][32][128];

    int blk = blockIdx.x;
    int b   = blk >> 7;              // NIN/32 = 128 tiles per batch
    int n0  = (blk & 127) * 32;
    int t   = threadIdx.x;
    int og  = t & 31;                // o = og*4 .. +3
    int ng  = t >> 5;                // n = n0 + ng*4 .. +3

    const float* inb = in + (size_t)b * CI * NIN;

    // per-thread staging addresses (wave-uniform LDS base + lane*16 layout)
    int xr = t >> 3, xc = (t & 7) * 4;          // X: 32k x 32n, 1 float4/thread
    const float* gx_base = &inb[(size_t)xr * NIN + n0 + xc];
    float* lx0 = &Xs[0][xr][xc];
    float* lx1 = &Xs[1][xr][xc];

    float acc[4][4] = {};

    // prologue: stage chunk 0
    gload16(gx_base, lx0);
    #pragma unroll
    for (int r = 0; r < 4; ++r) {
        int e = (r * 256 + t) * 4;
        gload16(WT + e, &Ws[0][0][0] + e);
    }
    __syncthreads();

    int buf = 0;
    for (int k0 = 0; k0 < CI; k0 += 32) {
        if (k0 + 32 < CI) {   // issue next chunk's async loads first
            if (buf == 0) gload16(gx_base + (size_t)(k0 + 32) * NIN, lx1);
            else          gload16(gx_base + (size_t)(k0 + 32) * NIN, lx0);
            const float* gw = WT + (size_t)(k0 + 32) * 128;
            float* lw = &Ws[buf ^ 1][0][0];
            #pragma unroll
            for (int r = 0; r < 4; ++r) {
                int e = (r * 256 + t) * 4;
                gload16(gw + e, lw + e);
            }
        }
        #pragma unroll
        for (int kk = 0; kk < 32; ++kk) {
            float w[4], xv[4];
            *(float4*)w  = *(const float4*)&Ws[buf][kk][og * 4];
            *(float4*)xv = *(const float4*)&Xs[buf][kk][ng * 4];
            #pragma unroll
            for (int oi = 0; oi < 4; ++oi)
                #pragma unroll
                for (int j = 0; j < 4; ++j)
                    acc[oi][j] = fmaf(w[oi], xv[j], acc[oi][j]);
        }
        __syncthreads();   // drains vmcnt (next chunk landed) + lgkm; protects overwrite
        buf ^= 1;
    }

    // epilogue: BN fold + relu
    #pragma unroll
    for (int oi = 0; oi < 4; ++oi) {
        float s  = svec[og * 4 + oi];
        float tt = tvec[og * 4 + oi];
        #pragma unroll
        for (int j = 0; j < 4; ++j)
            acc[oi][j] = fmaxf(fmaf(s, acc[oi][j], tt), 0.0f);
    }

    if (TOUT) {
        #pragma unroll
        for (int j = 0; j < 4; ++j) {
            int n = n0 + ng * 4 + j;
            float4 v = make_float4(acc[0][j], acc[1][j], acc[2][j], acc[3][j]);
            *(float4*)&out[((size_t)(b * NIN + n)) * COUT + og * 4] = v;
        }
    } else {
        #pragma unroll
        for (int oi = 0; oi < 4; ++oi) {
            int o = og * 4 + oi;
            float4 v = make_float4(acc[oi][0], acc[oi][1], acc[oi][2], acc[oi][3]);
            *(float4*)&out[((size_t)b * COUT + o) * NIN + n0 + ng * 4] = v;
        }
    }
}

// ---------------------------------------------------------------------------
// knn: per (b,m) find 3 smallest d2 over n (stable like top_k), store
// normalized inverse-distance weights + indices.
// block = 512 thr = 64 m x 8 scan-chunks of 512.
// Inner loop: 7-op exact distance (x2-prefolded), 1 v_cmp, then a DIVERGENT
// if (d<e2): exec-masked insert, skipped when no lane improves.
// ---------------------------------------------------------------------------
__global__ __launch_bounds__(512) void knn_kernel(
    const float4* __restrict__ packed, const float* __restrict__ xyzout,
    float* __restrict__ topw, int* __restrict__ topi)
{
    __shared__ float PD[8][64][3];
    __shared__ int   PI[8][64][3];

    int b  = blockIdx.y;
    int m0 = blockIdx.x * 64;
    int t  = threadIdx.x;
    int ml = t & 63, q = t >> 6;
    int m  = m0 + ml;

    size_t ob = ((size_t)b * MM + m) * 3;
    float x = xyzout[ob], y = xyzout[ob + 1], z = xyzout[ob + 2];
    float sm = __fadd_rn(__fadd_rn(__fmul_rn(x, x), __fmul_rn(y, y)), __fmul_rn(z, z));

    // q is wave-uniform (64-lane waves): force SGPR so packed[] scans are
    // scalar-cache loads (one s_load serves the whole wave).
    int qs = __builtin_amdgcn_readfirstlane(q);
    int nbase = qs * 512;
    const float4* pb = packed + (size_t)b * NIN + nbase;

    float e0 = 3.402823466e38f, e1 = 3.402823466e38f, e2 = 3.402823466e38f;
    int j0 = 0, j1 = 0, j2 = 0;

    for (int i0 = 0; i0 < 512; i0 += 8) {
        float4 pv[8];
        #pragma unroll
        for (int u = 0; u < 8; ++u) pv[u] = pb[i0 + u];   // scalar-load batch
        #pragma unroll
        for (int u = 0; u < 8; ++u) {
            float4 p = pv[u];   // (2x, 2y, 2z, sn)
            float dot2 = __fadd_rn(__fadd_rn(__fmul_rn(x, p.x), __fmul_rn(y, p.y)), __fmul_rn(z, p.z));
            float d    = __fsub_rn(__fadd_rn(sm, p.w), dot2);  // == ref bitwise
            if (d < e2) {   // divergent: exec-masked insert, branch skips when vccz
                int n = nbase + i0 + u;
                bool lt0 = d < e0, lt1 = d < e1;
                j2 = lt1 ? j1 : n;          // d<e2 implied by exec
                j1 = lt1 ? (lt0 ? j0 : n) : j1;
                j0 = lt0 ? n : j0;
                e2 = __builtin_amdgcn_fmed3f(d, e1, e2);
                e1 = __builtin_amdgcn_fmed3f(d, e0, e1);
                e0 = fminf(e0, d);
            }
        }
    }

    PD[q][ml][0] = e0; PD[q][ml][1] = e1; PD[q][ml][2] = e2;
    PI[q][ml][0] = j0; PI[q][ml][1] = j1; PI[q][ml][2] = j2;
    __syncthreads();

    if (t < 64) {
        float f0 = 3.402823466e38f, f1 = 3.402823466e38f, f2 = 3.402823466e38f;
        int i0 = 0, i1 = 0, i2 = 0;
        #pragma unroll
        for (int qq = 0; qq < 8; ++qq) {
            #pragma unroll
            for (int k = 0; k < 3; ++k) {
                float d = PD[qq][t][k];
                int   n = PI[qq][t][k];
                bool lt0 = d < f0, lt1 = d < f1, lt2 = d < f2;
                i2 = lt2 ? (lt1 ? i1 : n) : i2;
                i1 = lt1 ? (lt0 ? i0 : n) : i1;
                i0 = lt0 ? n : i0;
                f2 = __builtin_amdgcn_fmed3f(d, f1, f2);
                f1 = __builtin_amdgcn_fmed3f(d, f0, f1);
                f0 = fminf(f0, d);
            }
        }
        // clamp (ref: d2<0 -> 1e-7; also floors tiny positives, measure~zero)
        f0 = fmaxf(f0, 1e-7f); f1 = fmaxf(f1, 1e-7f); f2 = fmaxf(f2, 1e-7f);
        float iv0 = 1.0f / f0, iv1 = 1.0f / f1, iv2 = 1.0f / f2;
        float s = iv0 + iv1 + iv2;
        size_t wb = ((size_t)b * MM + m0 + t) * 3;
        topw[wb + 0] = iv0 / s; topw[wb + 1] = iv1 / s; topw[wb + 2] = iv2 / s;
        topi[wb + 0] = i0;      topi[wb + 1] = i1;      topi[wb + 2] = i2;
    }
}

// ---------------------------------------------------------------------------
// interp: out[b,o,m] = sum_k w[m,k] * featT[b, idx[m,k], o]
// block = 256 thr, 32 m per block; LDS bounce for gathered rows.
// ---------------------------------------------------------------------------
__global__ __launch_bounds__(256) void interp_kernel(
    const float* __restrict__ featT, const float* __restrict__ topw,
    const int* __restrict__ topi, float* __restrict__ out)
{
    __shared__ float G[32][388];   // [m][k*128+o], row stride 388 (4-mod-32 pad)
    __shared__ float Wl[32][4];

    int b  = blockIdx.y;
    int m0 = blockIdx.x * 32;
    int t  = threadIdx.x;

    if (t < 96) {
        int mm = t / 3, k = t - (t / 3) * 3;
        Wl[mm][k] = topw[((size_t)b * MM + m0 + mm) * 3 + k];
    }
    int lane = t & 31, r8 = t >> 5;
    #pragma unroll
    for (int pass = 0; pass < 12; ++pass) {
        int r  = pass * 8 + r8;          // 96 rows: (m,k)
        int mm = r / 3, k = r - (r / 3) * 3;
        int idx = topi[((size_t)b * MM + m0 + mm) * 3 + k];
        const float4 v = *(const float4*)&featT[((size_t)(b * NIN + idx)) * COUT + lane * 4];
        *(float4*)&G[mm][k * 128 + lane * 4] = v;
    }
    __syncthreads();

    int m  = t & 31;
    int obq = (t >> 5) * 16;
    float w0 = Wl[m][0], w1 = Wl[m][1], w2 = Wl[m][2];
    const float* Gm = &G[m][0];
    size_t outbase = ((size_t)b * COUT) * MM + m0 + m;
    #pragma unroll
    for (int oi = 0; oi < 16; ++oi) {
        int o = obq + oi;
        float v = w0 * Gm[o] + w1 * Gm[128 + o] + w2 * Gm[256 + o];
        out[outbase + (size_t)o * MM] = v;
    }
}

// ---------------------------------------------------------------------------
extern "C" void kernel_launch(void* const* d_in, const int* in_sizes, int n_in,
                              void* d_out, int out_size, void* d_ws, size_t ws_size,
                              hipStream_t stream)
{
    const float* rgb    = (const float*)d_in[0];
    const float* xyzin  = (const float*)d_in[1];
    const float* xyzout = (const float*)d_in[2];
    const float* w1  = (const float*)d_in[3];
    const float* b1  = (const float*)d_in[4];
    const float* g1  = (const float*)d_in[5];
    const float* be1 = (const float*)d_in[6];
    const float* rm1 = (const float*)d_in[7];
    const float* rv1 = (const float*)d_in[8];
    const float* w2  = (const float*)d_in[9];
    const float* b2  = (const float*)d_in[10];
    const float* g2  = (const float*)d_in[11];
    const float* be2 = (const float*)d_in[12];
    const float* rm2 = (const float*)d_in[13];
    const float* rv2 = (const float*)d_in[14];
    const float* w3  = (const float*)d_in[15];
    const float* b3  = (const float*)d_in[16];
    const float* g3  = (const float*)d_in[17];
    const float* be3 = (const float*)d_in[18];
    const float* rm3 = (const float*)d_in[19];
    const float* rv3 = (const float*)d_in[20];
    float* out = (float*)d_out;

    // workspace carve (floats)
    float* ws   = (float*)d_ws;
    float* WT1  = ws;                     // 32768
    float* WT2  = WT1 + 32768;            // 16384
    float* WT3  = WT2 + 16384;            // 16384
    float* st   = WT3 + 16384;            // 768
    float4* packed = (float4*)(st + 768); // 65536 floats
    float* featA = st + 768 + 65536;      // 2097152  (layer1 out, later featT)
    float* featB = featA + 2097152;       // 2097152  (layer2 out)
    float* topw  = featB + 2097152;       // 196608
    int*   topi  = (int*)(topw + 196608); // 196608

    prep_kernel<<<256, 256, 0, stream>>>(w1, w2, w3,
        b1, g1, be1, rm1, rv1,
        b2, g2, be2, rm2, rv2,
        b3, g3, be3, rm3, rv3,
        xyzin, WT1, WT2, WT3, st, packed);

    mlp_kernel<CIN, false><<<dim3(BB * (NIN / 32)), 256, 0, stream>>>(
        rgb, WT1, st + 0, st + 128, featA);
    mlp_kernel<COUT, false><<<dim3(BB * (NIN / 32)), 256, 0, stream>>>(
        featA, WT2, st + 256, st + 384, featB);
    mlp_kernel<COUT, true><<<dim3(BB * (NIN / 32)), 256, 0, stream>>>(
        featB, WT3, st + 512, st + 640, featA);   // featA now = featT (B,N,128)

    knn_kernel<<<dim3(MM / 64, BB), 512, 0, stream>>>(packed, xyzout, topw, topi);

    interp_kernel<<<dim3(MM / 32, BB), 256, 0, stream>>>(featA, topw, topi, out);
}